// Round 16
// baseline (14137.714 us; speedup 1.0000x reference)
//
#include <hip/hip_runtime.h>
#include <hip/hip_bf16.h>

typedef __bf16 bf16x8 __attribute__((ext_vector_type(8)));
typedef float  f32x4  __attribute__((ext_vector_type(4)));

#define MFMA16(a, b, c) __builtin_amdgcn_mfma_f32_16x16x32_bf16((a), (b), (c), 0, 0, 0)

static constexpr int Bz = 64, Tz = 512, Dz = 512, Hz = 1024;
static constexpr int NWG = 128;    // 128 WGs x 512 threads; waves 0-3 = L0, 4-7 = L1

static constexpr size_t LDS_BYTES = 131072;  // sWh0 [32][1024] + sWh1 [32][1024], kk-major

// ws layout, bf16 elements
static constexpr size_t N_W0X = 4096ull * 512;
static constexpr size_t N_W0H = 4096ull * 1024;
static constexpr size_t N_W1  = 4096ull * 2048;
static constexpr size_t N_Y0  = 64ull * 512 * 1024;
static constexpr size_t OFF_W0XH = 0;
static constexpr size_t OFF_W0XL = OFF_W0XH + N_W0X;
static constexpr size_t OFF_W0H  = OFF_W0XL + N_W0X;
static constexpr size_t OFF_W1   = OFF_W0H  + N_W0H;
static constexpr size_t OFF_Y0   = OFF_W1   + N_W1;
static constexpr size_t FLAGS_BYTE = (((OFF_Y0 + N_Y0) * 2) + 255) & ~(size_t)255;
static constexpr size_t H1S_BYTE   = FLAGS_BYTE + 4096;
static constexpr size_t WS_NEED    = H1S_BYTE + N_Y0 * 2;          // ~168 MB (proven)
// kk-major x-weight images (in the region r12 proved available: ws >= 235 MB)
static constexpr size_t IMG_BYTE   = H1S_BYTE + N_Y0 * 2;
static constexpr size_t N_IMG0     = 128ull * 16384;               // per-wg [16kk][1024]
static constexpr size_t N_IMG1     = 128ull * 32768;               // per-wg [32kk][1024]
static constexpr size_t IMG0H_OFF  = 0;
static constexpr size_t IMG0L_OFF  = IMG0H_OFF + N_IMG0;
static constexpr size_t IMG1_OFF   = IMG0L_OFF + N_IMG0;
static constexpr size_t WS_NEED_IMG = IMG_BYTE + (IMG1_OFF + N_IMG1) * 2;  // ~184 MB

static constexpr int STEP_ELEMS = 65536;

__device__ __forceinline__ float sigm(float x) { return 1.0f / (1.0f + __expf(-x)); }

__device__ __forceinline__ void st_agent_u32(void* p, unsigned v)
{ __hip_atomic_store((unsigned*)p, v, __ATOMIC_RELAXED, __HIP_MEMORY_SCOPE_AGENT); }
__device__ __forceinline__ void st_agent_f32(float* p, float v)
{ __hip_atomic_store(p, v, __ATOMIC_RELAXED, __HIP_MEMORY_SCOPE_AGENT); }

// ---------------- prep: bf16 weight copies + kk-major x-weight images ----------------
extern "C" __global__ void prep_split(const float* __restrict__ x,
                                      const float* __restrict__ W0,
                                      const float* __restrict__ W1,
                                      __bf16* __restrict__ ws,
                                      __bf16* __restrict__ img0h,
                                      __bf16* __restrict__ img0l,
                                      __bf16* __restrict__ img1)
{
    if (blockIdx.x == 0)
        for (int i = threadIdx.x; i < 1024; i += 256)
            ((unsigned*)((char*)ws + FLAGS_BYTE))[i] = 0u;

    __bf16* w0xh = ws + OFF_W0XH;
    __bf16* w0xl = ws + OFF_W0XL;
    __bf16* w0h  = ws + OFF_W0H;
    __bf16* w1c  = ws + OFF_W1;
    const size_t ntot = N_W0X + N_W0H + N_W1;
    const size_t stride = (size_t)gridDim.x * blockDim.x;
    for (size_t idx = (size_t)blockIdx.x * blockDim.x + threadIdx.x;
         idx < ntot; idx += stride) {
        if (idx < N_W0X) {
            size_t r = idx >> 9, c = idx & 511;
            float w = W0[r * 1536 + c];
            __bf16 hi = (__bf16)w;
            w0xh[idx] = hi;
            w0xl[idx] = (__bf16)(w - (float)hi);
        } else if (idx < N_W0X + N_W0H) {
            size_t i = idx - N_W0X;
            size_t r = i >> 10, c = i & 1023;
            w0h[i] = (__bf16)W0[r * 1536 + 512 + c];
        } else {
            size_t i = idx - N_W0X - N_W0H;
            w1c[i] = (__bf16)W1[i];
        }
    }
    if (img0h) {
        // W0x images, granule bits: [wg:7][c:5][kk:4][sub:2]; built from W0 directly
        for (size_t g = (size_t)blockIdx.x * blockDim.x + threadIdx.x;
             g < 262144; g += stride) {
            int wg = (int)(g >> 11), c = (g >> 6) & 31, kk = (g >> 2) & 15, sub = g & 3;
            size_t grow = (size_t)((c >> 3) * 1024 + wg * 8 + (c & 7));
            const float* src = W0 + grow * 1536 + (kk * 4 + sub) * 8;
            size_t dst = (size_t)wg * 16384 + kk * 1024 + c * 32
                       + ((sub * 8) ^ (((c >> 2) & 3) * 8));
#pragma unroll
            for (int e = 0; e < 8; ++e) {
                float v = src[e];
                __bf16 hi = (__bf16)v;
                img0h[dst + e] = hi;
                img0l[dst + e] = (__bf16)(v - (float)hi);
            }
        }
        // W1x image, granule bits: [wg:7][c:5][kk:5][sub:2]
        for (size_t g = (size_t)blockIdx.x * blockDim.x + threadIdx.x;
             g < 524288; g += stride) {
            int wg = (int)(g >> 12), c = (g >> 7) & 31, kk = (g >> 2) & 31, sub = g & 3;
            size_t grow = (size_t)((c >> 3) * 1024 + wg * 8 + (c & 7));
            const float* src = W1 + grow * 2048 + (kk * 4 + sub) * 8;
            size_t dst = (size_t)wg * 32768 + kk * 1024 + c * 32
                       + ((sub * 8) ^ (((c >> 2) & 3) * 8));
#pragma unroll
            for (int e = 0; e < 8; ++e) img1[dst + e] = (__bf16)src[e];
        }
    }
}

// ---------------- sync (verbatim r12) ----------------
__device__ __forceinline__ void publish(unsigned* p, unsigned v)
{
    asm volatile("s_waitcnt vmcnt(0)" ::: "memory");
    __hip_atomic_store(p, v, __ATOMIC_RELAXED, __HIP_MEMORY_SCOPE_AGENT);
}

__device__ __forceinline__ void wait_chunk32(const unsigned* flags, int base, unsigned target)
{
    const unsigned* p = flags + base + (threadIdx.x & 31);
    for (;;) {
        unsigned v = __hip_atomic_load(p, __ATOMIC_RELAXED, __HIP_MEMORY_SCOPE_AGENT);
        if (__all(v >= target)) break;
        __builtin_amdgcn_s_sleep(1);
    }
    asm volatile("" ::: "memory");
}

// x-part GEMM, on-the-fly hi/lo split (bit-identical to r12); weight stride parametrized
__device__ __forceinline__ void zx_fb(const float* __restrict__ xt,
    const __bf16* wxh0, const __bf16* wxl0,
    const __bf16* wxh1, const __bf16* wxl1, int wstr,
    f32x4& zx0, f32x4& zx1)
{
    f32x4 a0 = {0,0,0,0}, a1 = {0,0,0,0};
#pragma unroll 4
    for (int kk = 0; kk < Dz / 32; ++kk) {
        f32x4 va = *(const f32x4*)(xt + kk * 32);
        f32x4 vb = *(const f32x4*)(xt + kk * 32 + 4);
        bf16x8 ahi, alo;
#pragma unroll
        for (int e = 0; e < 4; ++e) {
            float v = va[e]; __bf16 h1 = (__bf16)v;
            ahi[e] = h1; alo[e] = (__bf16)(v - (float)h1);
            float w = vb[e]; __bf16 h2 = (__bf16)w;
            ahi[4 + e] = h2; alo[4 + e] = (__bf16)(w - (float)h2);
        }
        bf16x8 wh0 = *(const bf16x8*)(wxh0 + kk * wstr);
        bf16x8 wl0 = *(const bf16x8*)(wxl0 + kk * wstr);
        bf16x8 wh1 = *(const bf16x8*)(wxh1 + kk * wstr);
        bf16x8 wl1 = *(const bf16x8*)(wxl1 + kk * wstr);
        a0 = MFMA16(ahi, wh0, a0); a0 = MFMA16(alo, wh0, a0); a0 = MFMA16(ahi, wl0, a0);
        a1 = MFMA16(ahi, wh1, a1); a1 = MFMA16(alo, wh1, a1); a1 = MFMA16(ahi, wl1, a1);
    }
    zx0 = a0; zx1 = a1;
}

// gates + blocked full-line store (verbatim r12)
template <bool F32OUT>
__device__ __forceinline__ void gates_store(
    f32x4 za, f32x4 zb, float* cs, int lane, int l15, int rowBase,
    unsigned* yline, float* yf32, size_t rowStride)
{
    f32x4 pa, pb;
#pragma unroll
    for (int e = 0; e < 4; ++e) { pa[e] = __shfl_xor(za[e], 8, 64); pb[e] = __shfl_xor(zb[e], 8, 64); }
    const bool hi = (l15 & 8) != 0;
    int p01[2];
#pragma unroll
    for (int k2 = 0; k2 < 2; ++k2) {
        float zi, zf, zo, zg;
        if (hi) { zi = pa[2 + k2]; zf = za[2 + k2]; zo = pb[2 + k2]; zg = zb[2 + k2]; }
        else    { zi = za[k2];     zf = pa[k2];     zo = zb[k2];     zg = pb[k2];     }
        float cn = sigm(zf) * cs[k2] + sigm(zi) * tanhf(zg);
        float hn = sigm(zo) * tanhf(cn);
        cs[k2] = cn;
        if (F32OUT) {
            int b = rowBase + (hi ? 2 : 0) + k2;
            st_agent_f32(&yf32[(size_t)b * rowStride], hn);
        }
        __bf16 hb = (__bf16)hn;
        unsigned bits = (unsigned)__builtin_bit_cast(unsigned short, hb);
        unsigned par  = __shfl_down(bits, 1, 64);
        p01[k2] = (int)(bits | (par << 16));
    }
    if (yline) {
        int r    = lane >> 2;
        int srcl = ((r >> 2) << 4) | (((r >> 1) & 1) << 3) | ((lane & 3) << 1);
        unsigned v0 = (unsigned)__builtin_amdgcn_ds_bpermute(srcl * 4, p01[0]);
        unsigned v1 = (unsigned)__builtin_amdgcn_ds_bpermute(srcl * 4, p01[1]);
        st_agent_u32(yline + lane, (r & 1) ? v1 : v0);
    }
}

// ---------------- L0 wave body (m = wave, verbatim r12 layer0 with wave->m) ----------
__device__ __forceinline__ void layer0_wave(
    int m, int lane, int l15, int lg, int wg, int j0,
    const float* __restrict__ x,
    const __bf16* sWh0,
    const __bf16* __restrict__ ix_h, const __bf16* __restrict__ ix_l, int xstr,
    const float* __restrict__ b0,
    __bf16* y0, unsigned* flags0)
{
    const __bf16* wxh[2]; const __bf16* wxl[2]; const __bf16* whp[2]; float bv[2];
#pragma unroll
    for (int tn = 0; tn < 2; ++tn) {
        int c = tn * 16 + l15;
        int lofs = c * 32 + ((lg * 8) ^ (((c >> 2) & 3) * 8));
        whp[tn] = sWh0 + lofs;
        if (xstr == 1024) {
            wxh[tn] = ix_h + (size_t)wg * 16384 + lofs;
            wxl[tn] = ix_l + (size_t)wg * 16384 + lofs;
        } else {   // row-major fallback
            size_t grow = (size_t)((c >> 3) * 1024 + j0 + (c & 7));
            wxh[tn] = ix_h + grow * Dz + lg * 8;
            wxl[tn] = ix_l + grow * Dz + lg * 8;
        }
        bv[tn] = b0[(c >> 3) * Hz + j0 + (c & 7)];
    }
    const float*  xp  = x  + (size_t)(m * 16 + l15) * Tz * Dz + lg * 8;
    const __bf16* hp0 = y0 + m * 128 + l15 * 8 + lg * 512;

    const unsigned* flw = flags0 + m * 128;
    unsigned* myflag     = flags0 + m * 128 + wg;

    float cs[2] = {0.f, 0.f};
    f32x4 zx0, zx1;
    zx_fb(xp, wxh[0], wxl[0], wxh[1], wxl[1], xstr, zx0, zx1);

    for (int s = 0; s < Tz; ++s) {
        f32x4 ah0 = {0,0,0,0}, ah1 = {0,0,0,0};
        if (s > 0) {
            const __bf16* ht = hp0 + (size_t)(s - 1) * STEP_ELEMS;
            for (int c4 = 0; c4 < 4; ++c4) {
                wait_chunk32(flw, 32 * c4, (unsigned)s);
#pragma unroll
                for (int kk = 8 * c4; kk < 8 * c4 + 8; ++kk) {
                    bf16x8 a = *(const bf16x8*)(ht + kk * 2048);
                    ah0 = MFMA16(a, *(const bf16x8*)(whp[0] + kk * 1024), ah0);
                    ah1 = MFMA16(a, *(const bf16x8*)(whp[1] + kk * 1024), ah1);
                }
            }
        }
        f32x4 za, zb;
#pragma unroll
        for (int e = 0; e < 4; ++e) { za[e] = zx0[e] + ah0[e] + bv[0]; zb[e] = zx1[e] + ah1[e] + bv[1]; }

        unsigned* yline = (unsigned*)y0 + (size_t)s * (STEP_ELEMS / 2) + wg * 256 + m * 64;
        gates_store<false>(za, zb, cs, lane, l15, m * 16 + lg * 4, yline, nullptr, 0);

        publish(myflag, (unsigned)(s + 1));
        if (s < Tz - 1)
            zx_fb(xp + (size_t)(s + 1) * Dz, wxh[0], wxl[0], wxh[1], wxl[1], xstr, zx0, zx1);
    }
}

// ---------------- L1 wave body (m = wave-4, verbatim r12 layer1 with wave->m) --------
__device__ __forceinline__ void layer1_wave(
    int m, int lane, int l15, int lg, int wg, int j0,
    const __bf16* __restrict__ y0,
    const __bf16* sWh1,
    const __bf16* __restrict__ ix1, int xstr,
    const float* __restrict__ b1,
    float* out, __bf16* h1s, unsigned* flags0, unsigned* flags1)
{
    const __bf16* wxp[2]; const __bf16* whp[2]; float bv[2];
#pragma unroll
    for (int tn = 0; tn < 2; ++tn) {
        int c = tn * 16 + l15;
        int lofs = c * 32 + ((lg * 8) ^ (((c >> 2) & 3) * 8));
        whp[tn] = sWh1 + lofs;
        if (xstr == 1024) {
            wxp[tn] = ix1 + (size_t)wg * 32768 + lofs;
        } else {   // row-major fallback into W1 bf16 copy (x-part cols 0..1023)
            size_t grow = (size_t)((c >> 3) * 1024 + j0 + (c & 7));
            wxp[tn] = ix1 + grow * 2048 + lg * 8;
        }
        bv[tn] = b1[(c >> 3) * Hz + j0 + (c & 7)];
    }
    const __bf16* xp0 = y0 + m * 128 + l15 * 8 + lg * 512;
    const float*  hpf = out + (size_t)(m * 16 + l15) * Tz * Hz + lg * 8;
    const __bf16* hs0 = h1s ? h1s + m * 128 + l15 * 8 + lg * 512 : nullptr;

    const unsigned* fl0w = flags0 + m * 128;
    const unsigned* fl1w = flags1 + m * 128;
    unsigned* myflag      = flags1 + m * 128 + wg;

    float cs[2] = {0.f, 0.f};

    for (int s = 1; s <= Tz; ++s) {
        const int t = s - 1;
        f32x4 ax0 = {bv[0], bv[0], bv[0], bv[0]};
        f32x4 ax1 = {bv[1], bv[1], bv[1], bv[1]};

        if (t > 0) {
            if (hs0) {
                const __bf16* ht = hs0 + (size_t)(t - 1) * STEP_ELEMS;
                for (int c4 = 0; c4 < 4; ++c4) {
                    wait_chunk32(fl1w, 32 * c4, (unsigned)(s - 1));
#pragma unroll
                    for (int kk = 8 * c4; kk < 8 * c4 + 8; ++kk) {
                        bf16x8 a = *(const bf16x8*)(ht + kk * 2048);
                        ax0 = MFMA16(a, *(const bf16x8*)(whp[0] + kk * 1024), ax0);
                        ax1 = MFMA16(a, *(const bf16x8*)(whp[1] + kk * 1024), ax1);
                    }
                }
            } else {
                const float* ht = hpf + (size_t)(t - 1) * Hz;
                for (int c4 = 0; c4 < 4; ++c4) {
                    wait_chunk32(fl1w, 32 * c4, (unsigned)(s - 1));
#pragma unroll
                    for (int kk = 8 * c4; kk < 8 * c4 + 8; ++kk) {
                        f32x4 va = *(const f32x4*)(ht + kk * 32);
                        f32x4 vb = *(const f32x4*)(ht + kk * 32 + 4);
                        bf16x8 a;
#pragma unroll
                        for (int e = 0; e < 4; ++e) { a[e] = (__bf16)va[e]; a[4 + e] = (__bf16)vb[e]; }
                        ax0 = MFMA16(a, *(const bf16x8*)(whp[0] + kk * 1024), ax0);
                        ax1 = MFMA16(a, *(const bf16x8*)(whp[1] + kk * 1024), ax1);
                    }
                }
            }
        }
        {
            const __bf16* xt = xp0 + (size_t)t * STEP_ELEMS;
            for (int c4 = 0; c4 < 4; ++c4) {
                wait_chunk32(fl0w, 32 * c4, (unsigned)s);
#pragma unroll
                for (int kk = 8 * c4; kk < 8 * c4 + 8; ++kk) {
                    bf16x8 a = *(const bf16x8*)(xt + kk * 2048);
                    ax0 = MFMA16(a, *(const bf16x8*)(wxp[0] + kk * (xstr == 1024 ? 1024 : 32)), ax0);
                    ax1 = MFMA16(a, *(const bf16x8*)(wxp[1] + kk * (xstr == 1024 ? 1024 : 32)), ax1);
                }
            }
        }

        unsigned* hline = h1s ? (unsigned*)h1s + (size_t)t * (STEP_ELEMS / 2) + wg * 256 + m * 64
                              : nullptr;
        gates_store<true>(ax0, ax1, cs, lane, l15, m * 16 + lg * 4,
                          hline, out + (size_t)t * Hz + j0 + (l15 & 7), (size_t)Tz * Hz);

        if (s < Tz) publish(myflag, (unsigned)s);
    }
}

extern "C" __global__ void __launch_bounds__(512, 1)
lstm2(const float* __restrict__ x,
      const float* __restrict__ b0,
      const float* __restrict__ b1,
      __bf16* ws,
      float* out,
      __bf16* h1s,
      const __bf16* __restrict__ img0h,
      const __bf16* __restrict__ img0l,
      const __bf16* __restrict__ img1)
{
    extern __shared__ char lds_raw[];
    __bf16* sWh0 = (__bf16*)lds_raw;             // [32 kk][1024], swizzled
    __bf16* sWh1 = (__bf16*)(lds_raw + 65536);
    unsigned* flags0 = (unsigned*)((char*)ws + FLAGS_BYTE);
    unsigned* flags1 = (unsigned*)((char*)ws + FLAGS_BYTE + 2048);

    const int tid  = threadIdx.x;
    const int wave = tid >> 6, lane = tid & 63, l15 = lane & 15, lg = lane >> 4;
    const int wg   = blockIdx.x;
    const int j0   = wg * 8;

    const __bf16* w0h = ws + OFF_W0H;
    const __bf16* w1c = ws + OFF_W1;
    __bf16* y0        = ws + OFF_Y0;

    // stage BOTH layers' h-weights, kk-major+swizzled (512 threads)
    for (int idx = tid; idx < 4096; idx += 512) {
        int r = idx >> 7, k8 = idx & 127;
        int kk = k8 >> 2, sub = k8 & 3;
        int dst = kk * 1024 + r * 32 + ((sub * 8) ^ (((r >> 2) & 3) * 8));
        size_t grow = (size_t)((r >> 3) * Hz + j0 + (r & 7));
        *(bf16x8*)(sWh0 + dst) = *(const bf16x8*)(w0h + grow * Hz + k8 * 8);
        *(bf16x8*)(sWh1 + dst) = *(const bf16x8*)(w1c + grow * 2048 + 1024 + k8 * 8);
    }
    __syncthreads();   // only barrier; waves fully decoupled afterwards

    const bool haveImg = (img0h != nullptr);
    if (wave < 4) {
        const __bf16* ih = haveImg ? img0h : ws + OFF_W0XH;
        const __bf16* il = haveImg ? img0l : ws + OFF_W0XL;
        layer0_wave(wave, lane, l15, lg, wg, j0, x, sWh0,
                    ih, il, haveImg ? 1024 : 32, b0, y0, flags0);
    } else {
        const __bf16* i1 = haveImg ? img1 : w1c;
        layer1_wave(wave - 4, lane, l15, lg, wg, j0, y0, sWh1,
                    i1, haveImg ? 1024 : 32, b1, out, h1s, flags0, flags1);
    }
}

extern "C" void kernel_launch(void* const* d_in, const int* in_sizes, int n_in,
                              void* d_out, int out_size, void* d_ws, size_t ws_size,
                              hipStream_t stream)
{
    const float* x  = (const float*)d_in[0];
    const float* W0 = (const float*)d_in[1];
    const float* b0 = (const float*)d_in[2];
    const float* W1 = (const float*)d_in[3];
    const float* b1 = (const float*)d_in[4];
    float* out = (float*)d_out;
    __bf16* ws = (__bf16*)d_ws;
    __bf16* h1s = (ws_size >= WS_NEED) ? (__bf16*)((char*)ws + H1S_BYTE) : nullptr;

    __bf16* imgBase = (ws_size >= WS_NEED_IMG) ? (__bf16*)((char*)ws + IMG_BYTE) : nullptr;
    __bf16* img0h = imgBase ? imgBase + IMG0H_OFF : nullptr;
    __bf16* img0l = imgBase ? imgBase + IMG0L_OFF : nullptr;
    __bf16* img1  = imgBase ? imgBase + IMG1_OFF  : nullptr;

    (void)hipFuncSetAttribute((const void*)lstm2,
                        hipFuncAttributeMaxDynamicSharedMemorySize, (int)LDS_BYTES);

    hipLaunchKernelGGL(prep_split, dim3(2048), dim3(256), 0, stream,
                       x, W0, W1, ws, img0h, img0l, img1);

    const __bf16* i0h = img0h; const __bf16* i0l = img0l; const __bf16* i1 = img1;
    void* args[] = { (void*)&x, (void*)&b0, (void*)&b1, (void*)&ws, (void*)&out,
                     (void*)&h1s, (void*)&i0h, (void*)&i0l, (void*)&i1 };
    (void)hipLaunchCooperativeKernel(reinterpret_cast<void*>(lstm2),
                               dim3(NWG), dim3(512), args, LDS_BYTES, stream);
}

// Round 17
// 8944.636 us; speedup vs baseline: 1.5806x; 1.5806x over previous
//
#include <hip/hip_runtime.h>
#include <hip/hip_bf16.h>

typedef __bf16 bf16x8 __attribute__((ext_vector_type(8)));
typedef float  f32x4  __attribute__((ext_vector_type(4)));

#define MFMA16(a, b, c) __builtin_amdgcn_mfma_f32_16x16x32_bf16((a), (b), (c), 0, 0, 0)

static constexpr int Bz = 64, Tz = 512, Dz = 512, Hz = 1024;
static constexpr int NWG0 = 128;
static constexpr int NWGT = 256;
static constexpr int NJ   = 8;

static constexpr int PXL = 512 + 8;
static constexpr int PHL = 1024 + 8;
static constexpr size_t LDS_BYTES = (size_t)(2 * 32 * PXL + 32 * PHL) * 2;  // 132608

// ws layout, bf16 elements
static constexpr size_t N_W0X = 4096ull * 512;
static constexpr size_t N_W0H = 4096ull * 1024;
static constexpr size_t N_W1  = 4096ull * 2048;
static constexpr size_t N_Y0  = 64ull * 512 * 1024;
static constexpr size_t N_X   = 64ull * 512 * 512;
static constexpr size_t OFF_W0XH = 0;
static constexpr size_t OFF_W0XL = OFF_W0XH + N_W0X;
static constexpr size_t OFF_W0H  = OFF_W0XL + N_W0X;
static constexpr size_t OFF_W1   = OFF_W0H  + N_W0H;
static constexpr size_t OFF_Y0   = OFF_W1   + N_W1;
static constexpr size_t FLAGS_BYTE = (((OFF_Y0 + N_Y0) * 2) + 255) & ~(size_t)255;
static constexpr size_t H1S_BYTE   = FLAGS_BYTE + 4096;
static constexpr size_t WS_NEED    = H1S_BYTE + N_Y0 * 2;
static constexpr size_t XHI_BYTE   = H1S_BYTE + N_Y0 * 2;
static constexpr size_t XLO_BYTE   = XHI_BYTE + N_X * 2;
static constexpr size_t WS_NEED_X  = XLO_BYTE + N_X * 2;

static constexpr int STEP_ELEMS = 65536;

__device__ __forceinline__ float sigm(float x) { return 1.0f / (1.0f + __expf(-x)); }

__device__ __forceinline__ void st_agent_u32(void* p, unsigned v)
{ __hip_atomic_store((unsigned*)p, v, __ATOMIC_RELAXED, __HIP_MEMORY_SCOPE_AGENT); }
__device__ __forceinline__ void st_agent_f32(float* p, float v)
{ __hip_atomic_store(p, v, __ATOMIC_RELAXED, __HIP_MEMORY_SCOPE_AGENT); }

// ---------------- prep (verbatim r12) ----------------
extern "C" __global__ void prep_split(const float* __restrict__ x,
                                      const float* __restrict__ W0,
                                      const float* __restrict__ W1,
                                      __bf16* __restrict__ ws,
                                      __bf16* __restrict__ xhi,
                                      __bf16* __restrict__ xlo)
{
    if (blockIdx.x == 0)
        for (int i = threadIdx.x; i < 1024; i += 256)
            ((unsigned*)((char*)ws + FLAGS_BYTE))[i] = 0u;

    __bf16* w0xh = ws + OFF_W0XH;
    __bf16* w0xl = ws + OFF_W0XL;
    __bf16* w0h  = ws + OFF_W0H;
    __bf16* w1c  = ws + OFF_W1;
    const size_t ntot = N_W0X + N_W0H + N_W1;
    const size_t stride = (size_t)gridDim.x * blockDim.x;
    for (size_t idx = (size_t)blockIdx.x * blockDim.x + threadIdx.x;
         idx < ntot; idx += stride) {
        if (idx < N_W0X) {
            size_t r = idx >> 9, c = idx & 511;
            float w = W0[r * 1536 + c];
            __bf16 hi = (__bf16)w;
            w0xh[idx] = hi;
            w0xl[idx] = (__bf16)(w - (float)hi);
        } else if (idx < N_W0X + N_W0H) {
            size_t i = idx - N_W0X;
            size_t r = i >> 10, c = i & 1023;
            w0h[i] = (__bf16)W0[r * 1536 + 512 + c];
        } else {
            size_t i = idx - N_W0X - N_W0H;
            w1c[i] = (__bf16)W1[i];
        }
    }
    if (xhi) {
        for (size_t idx = (size_t)blockIdx.x * blockDim.x + threadIdx.x;
             idx < N_X; idx += stride) {
            float v = x[idx];
            __bf16 hi = (__bf16)v;
            xhi[idx] = hi;
            xlo[idx] = (__bf16)(v - (float)hi);
        }
    }
}

// ---------------- sync: merged single-poll waits ----------------
__device__ __forceinline__ void publish(unsigned* p, unsigned v)
{
    asm volatile("s_waitcnt vmcnt(0)" ::: "memory");
    __hip_atomic_store(p, v, __ATOMIC_RELAXED, __HIP_MEMORY_SCOPE_AGENT);
}

// all 128 flags of one wave-row (4 lines; 2 loads/lane; ONE serialized round-trip)
__device__ __forceinline__ void wait_all128(const unsigned* row, unsigned target)
{
    const unsigned* p = row + (threadIdx.x & 63);
    for (;;) {
        unsigned a = __hip_atomic_load(p,      __ATOMIC_RELAXED, __HIP_MEMORY_SCOPE_AGENT);
        unsigned b = __hip_atomic_load(p + 64, __ATOMIC_RELAXED, __HIP_MEMORY_SCOPE_AGENT);
        if (__all(a >= target && b >= target)) break;
        __builtin_amdgcn_s_sleep(1);
    }
    asm volatile("" ::: "memory");
}

// two wave-rows with independent targets in one poll loop (L1: flags1 AND flags0)
__device__ __forceinline__ void wait_dual128(const unsigned* rowA, unsigned ta,
                                             const unsigned* rowB, unsigned tb)
{
    const unsigned* pa = rowA + (threadIdx.x & 63);
    const unsigned* pb = rowB + (threadIdx.x & 63);
    for (;;) {
        unsigned a0 = __hip_atomic_load(pa,      __ATOMIC_RELAXED, __HIP_MEMORY_SCOPE_AGENT);
        unsigned a1 = __hip_atomic_load(pa + 64, __ATOMIC_RELAXED, __HIP_MEMORY_SCOPE_AGENT);
        unsigned b0 = __hip_atomic_load(pb,      __ATOMIC_RELAXED, __HIP_MEMORY_SCOPE_AGENT);
        unsigned b1 = __hip_atomic_load(pb + 64, __ATOMIC_RELAXED, __HIP_MEMORY_SCOPE_AGENT);
        if (__all(a0 >= ta && a1 >= ta && b0 >= tb && b1 >= tb)) break;
        __builtin_amdgcn_s_sleep(1);
    }
    asm volatile("" ::: "memory");
}

// x-part GEMM, pre-split inputs (verbatim r12)
__device__ __forceinline__ void zx_ps(const __bf16* __restrict__ xh,
                                      const __bf16* __restrict__ xl,
    const __bf16* wxh0, const __bf16* wxl0,
    const __bf16* wxh1, const __bf16* wxl1,
    f32x4& zx0, f32x4& zx1)
{
    f32x4 a0 = {0,0,0,0}, a1 = {0,0,0,0};
#pragma unroll 4
    for (int kk = 0; kk < Dz / 32; ++kk) {
        bf16x8 ahi = *(const bf16x8*)(xh + kk * 32);
        bf16x8 alo = *(const bf16x8*)(xl + kk * 32);
        bf16x8 wh0 = *(const bf16x8*)(wxh0 + kk * 32);
        bf16x8 wl0 = *(const bf16x8*)(wxl0 + kk * 32);
        bf16x8 wh1 = *(const bf16x8*)(wxh1 + kk * 32);
        bf16x8 wl1 = *(const bf16x8*)(wxl1 + kk * 32);
        a0 = MFMA16(ahi, wh0, a0); a0 = MFMA16(alo, wh0, a0); a0 = MFMA16(ahi, wl0, a0);
        a1 = MFMA16(ahi, wh1, a1); a1 = MFMA16(alo, wh1, a1); a1 = MFMA16(ahi, wl1, a1);
    }
    zx0 = a0; zx1 = a1;
}

__device__ __forceinline__ void zx_fb(const float* __restrict__ xt,
    const __bf16* wxh0, const __bf16* wxl0,
    const __bf16* wxh1, const __bf16* wxl1,
    f32x4& zx0, f32x4& zx1)
{
    f32x4 a0 = {0,0,0,0}, a1 = {0,0,0,0};
#pragma unroll 4
    for (int kk = 0; kk < Dz / 32; ++kk) {
        f32x4 va = *(const f32x4*)(xt + kk * 32);
        f32x4 vb = *(const f32x4*)(xt + kk * 32 + 4);
        bf16x8 ahi, alo;
#pragma unroll
        for (int e = 0; e < 4; ++e) {
            float v = va[e]; __bf16 h1 = (__bf16)v;
            ahi[e] = h1; alo[e] = (__bf16)(v - (float)h1);
            float w = vb[e]; __bf16 h2 = (__bf16)w;
            ahi[4 + e] = h2; alo[4 + e] = (__bf16)(w - (float)h2);
        }
        bf16x8 wh0 = *(const bf16x8*)(wxh0 + kk * 32);
        bf16x8 wl0 = *(const bf16x8*)(wxl0 + kk * 32);
        bf16x8 wh1 = *(const bf16x8*)(wxh1 + kk * 32);
        bf16x8 wl1 = *(const bf16x8*)(wxl1 + kk * 32);
        a0 = MFMA16(ahi, wh0, a0); a0 = MFMA16(alo, wh0, a0); a0 = MFMA16(ahi, wl0, a0);
        a1 = MFMA16(ahi, wh1, a1); a1 = MFMA16(alo, wh1, a1); a1 = MFMA16(ahi, wl1, a1);
    }
    zx0 = a0; zx1 = a1;
}

// gates + blocked full-line store (verbatim r12)
template <bool F32OUT>
__device__ __forceinline__ void gates_store(
    f32x4 za, f32x4 zb, float* cs, int lane, int l15, int rowBase,
    unsigned* yline, float* yf32, size_t rowStride)
{
    f32x4 pa, pb;
#pragma unroll
    for (int e = 0; e < 4; ++e) { pa[e] = __shfl_xor(za[e], 8, 64); pb[e] = __shfl_xor(zb[e], 8, 64); }
    const bool hi = (l15 & 8) != 0;
    int p01[2];
#pragma unroll
    for (int k2 = 0; k2 < 2; ++k2) {
        float zi, zf, zo, zg;
        if (hi) { zi = pa[2 + k2]; zf = za[2 + k2]; zo = pb[2 + k2]; zg = zb[2 + k2]; }
        else    { zi = za[k2];     zf = pa[k2];     zo = zb[k2];     zg = pb[k2];     }
        float cn = sigm(zf) * cs[k2] + sigm(zi) * tanhf(zg);
        float hn = sigm(zo) * tanhf(cn);
        cs[k2] = cn;
        if (F32OUT) {
            int b = rowBase + (hi ? 2 : 0) + k2;
            st_agent_f32(&yf32[(size_t)b * rowStride], hn);
        }
        __bf16 hb = (__bf16)hn;
        unsigned bits = (unsigned)__builtin_bit_cast(unsigned short, hb);
        unsigned par  = __shfl_down(bits, 1, 64);
        p01[k2] = (int)(bits | (par << 16));
    }
    if (yline) {
        int r    = lane >> 2;
        int srcl = ((r >> 2) << 4) | (((r >> 1) & 1) << 3) | ((lane & 3) << 1);
        unsigned v0 = (unsigned)__builtin_amdgcn_ds_bpermute(srcl * 4, p01[0]);
        unsigned v1 = (unsigned)__builtin_amdgcn_ds_bpermute(srcl * 4, p01[1]);
        st_agent_u32(yline + lane, (r & 1) ? v1 : v0);
    }
}

// ---------------- layer 0 ----------------
__device__ __forceinline__ void layer0(
    const float* __restrict__ x,
    const __bf16* __restrict__ xhi, const __bf16* __restrict__ xlo,
    const __bf16* __restrict__ w0xh, const __bf16* __restrict__ w0xl,
    const __bf16* __restrict__ w0h,  const float* __restrict__ b0,
    __bf16* y0, __bf16* wtile, unsigned* flags0)
{
    const int tid  = threadIdx.x;
    const int wave = tid >> 6, lane = tid & 63, l15 = lane & 15, lg = lane >> 4;
    const int wg   = blockIdx.x;
    const int j0   = wg * NJ;

    __bf16* sWXH = wtile;
    __bf16* sWXL = wtile + 32 * PXL;
    __bf16* sWH  = wtile + 64 * PXL;
    for (int idx = tid; idx < 32 * (Dz / 8); idx += 256) {
        int r = idx >> 6, kc = (idx & 63) * 8;
        size_t grow = (size_t)((r >> 3) * Hz + j0 + (r & 7));
        *(bf16x8*)(sWXH + r * PXL + kc) = *(const bf16x8*)(w0xh + grow * Dz + kc);
        *(bf16x8*)(sWXL + r * PXL + kc) = *(const bf16x8*)(w0xl + grow * Dz + kc);
    }
    for (int idx = tid; idx < 32 * (Hz / 8); idx += 256) {
        int r = idx >> 7, kc = (idx & 127) * 8;
        size_t grow = (size_t)((r >> 3) * Hz + j0 + (r & 7));
        *(bf16x8*)(sWH + r * PHL + kc) = *(const bf16x8*)(w0h + grow * Hz + kc);
    }
    __syncthreads();

    const __bf16* wxh[2]; const __bf16* wxl[2]; const __bf16* whp[2]; float bv[2];
#pragma unroll
    for (int tn = 0; tn < 2; ++tn) {
        int c = tn * 16 + l15;
        wxh[tn] = sWXH + c * PXL + lg * 8;
        wxl[tn] = sWXL + c * PXL + lg * 8;
        whp[tn] = sWH  + c * PHL + lg * 8;
        bv[tn]  = b0[(c >> 3) * Hz + j0 + (c & 7)];
    }
    const int bA = wave * 16 + l15;
    const float*  xp  = x + (size_t)bA * Tz * Dz + lg * 8;
    const __bf16* xph = xhi ? xhi + (size_t)bA * Tz * Dz + lg * 8 : nullptr;
    const __bf16* xpl = xlo ? xlo + (size_t)bA * Tz * Dz + lg * 8 : nullptr;
    const __bf16* hp0 = y0 + wave * 128 + l15 * 8 + lg * 512;

    const unsigned* flw = flags0 + wave * 128;
    unsigned* myflag     = flags0 + wave * 128 + wg;

    float cs[2] = {0.f, 0.f};
    f32x4 zx0, zx1;
    if (xph) zx_ps(xph, xpl, wxh[0], wxl[0], wxh[1], wxl[1], zx0, zx1);
    else     zx_fb(xp,       wxh[0], wxl[0], wxh[1], wxl[1], zx0, zx1);

    for (int s = 0; s < Tz; ++s) {
        f32x4 ah0 = {0,0,0,0}, ah1 = {0,0,0,0};
        if (s > 0) {
            wait_all128(flw, (unsigned)s);          // ONE poll round for all producers
            const __bf16* ht = hp0 + (size_t)(s - 1) * STEP_ELEMS;
#pragma unroll
            for (int kk = 0; kk < 32; ++kk) {       // all 32 h-loads issue together
                bf16x8 a = *(const bf16x8*)(ht + kk * 2048);
                ah0 = MFMA16(a, *(const bf16x8*)(whp[0] + kk * 32), ah0);
                ah1 = MFMA16(a, *(const bf16x8*)(whp[1] + kk * 32), ah1);
            }
        }
        f32x4 za, zb;
#pragma unroll
        for (int e = 0; e < 4; ++e) { za[e] = zx0[e] + ah0[e] + bv[0]; zb[e] = zx1[e] + ah1[e] + bv[1]; }

        unsigned* yline = (unsigned*)y0 + (size_t)s * (STEP_ELEMS / 2) + wg * 256 + wave * 64;
        gates_store<false>(za, zb, cs, lane, l15, wave * 16 + lg * 4, yline, nullptr, 0);

        publish(myflag, (unsigned)(s + 1));
        if (s < Tz - 1) {
            if (xph) zx_ps(xph + (size_t)(s + 1) * Dz, xpl + (size_t)(s + 1) * Dz,
                           wxh[0], wxl[0], wxh[1], wxl[1], zx0, zx1);
            else     zx_fb(xp + (size_t)(s + 1) * Dz,
                           wxh[0], wxl[0], wxh[1], wxl[1], zx0, zx1);
        }
    }
}

// ---------------- layer 1 ----------------
__device__ __forceinline__ void layer1(
    const __bf16* __restrict__ y0, const __bf16* __restrict__ w1c,
    const float* __restrict__ b1, float* out, __bf16* h1s,
    __bf16* wtile, unsigned* flags0, unsigned* flags1)
{
    const int tid  = threadIdx.x;
    const int wave = tid >> 6, lane = tid & 63, l15 = lane & 15, lg = lane >> 4;
    const int wg   = blockIdx.x - NWG0;
    const int j0   = wg * NJ;

    __bf16* sWX = wtile;
    __bf16* sWH = wtile + 32 * PHL;
    for (int idx = tid; idx < 32 * (Hz / 8); idx += 256) {
        int r = idx >> 7, kc = (idx & 127) * 8;
        size_t grow = (size_t)((r >> 3) * Hz + j0 + (r & 7));
        const __bf16* srow = w1c + grow * 2048;
        *(bf16x8*)(sWX + r * PHL + kc) = *(const bf16x8*)(srow + kc);
        *(bf16x8*)(sWH + r * PHL + kc) = *(const bf16x8*)(srow + 1024 + kc);
    }
    __syncthreads();

    const __bf16* wxp[2]; const __bf16* whp[2]; float bv[2];
#pragma unroll
    for (int tn = 0; tn < 2; ++tn) {
        int c = tn * 16 + l15;
        wxp[tn] = sWX + c * PHL + lg * 8;
        whp[tn] = sWH + c * PHL + lg * 8;
        bv[tn]  = b1[(c >> 3) * Hz + j0 + (c & 7)];
    }
    const int bA = wave * 16 + l15;
    const __bf16* xp0 = y0 + wave * 128 + l15 * 8 + lg * 512;
    const float*  hpf = out + (size_t)bA * Tz * Hz + lg * 8;
    const __bf16* hs0 = h1s ? h1s + wave * 128 + l15 * 8 + lg * 512 : nullptr;

    const unsigned* fl0w = flags0 + wave * 128;
    const unsigned* fl1w = flags1 + wave * 128;
    unsigned* myflag      = flags1 + wave * 128 + wg;

    float cs[2] = {0.f, 0.f};

    for (int s = 1; s <= Tz; ++s) {
        const int t = s - 1;
        f32x4 ax0 = {bv[0], bv[0], bv[0], bv[0]};
        f32x4 ax1 = {bv[1], bv[1], bv[1], bv[1]};

        // ONE merged poll round for both dependencies
        if (t > 0) wait_dual128(fl1w, (unsigned)(s - 1), fl0w, (unsigned)s);
        else       wait_all128(fl0w, (unsigned)s);

        if (t > 0) {
            if (hs0) {
                const __bf16* ht = hs0 + (size_t)(t - 1) * STEP_ELEMS;
#pragma unroll
                for (int kk = 0; kk < 32; ++kk) {
                    bf16x8 a = *(const bf16x8*)(ht + kk * 2048);
                    ax0 = MFMA16(a, *(const bf16x8*)(whp[0] + kk * 32), ax0);
                    ax1 = MFMA16(a, *(const bf16x8*)(whp[1] + kk * 32), ax1);
                }
            } else {
                const float* ht = hpf + (size_t)(t - 1) * Hz;
#pragma unroll
                for (int kk = 0; kk < 32; ++kk) {
                    f32x4 va = *(const f32x4*)(ht + kk * 32);
                    f32x4 vb = *(const f32x4*)(ht + kk * 32 + 4);
                    bf16x8 a;
#pragma unroll
                    for (int e = 0; e < 4; ++e) { a[e] = (__bf16)va[e]; a[4 + e] = (__bf16)vb[e]; }
                    ax0 = MFMA16(a, *(const bf16x8*)(whp[0] + kk * 32), ax0);
                    ax1 = MFMA16(a, *(const bf16x8*)(whp[1] + kk * 32), ax1);
                }
            }
        }
        {
            const __bf16* xt = xp0 + (size_t)t * STEP_ELEMS;
#pragma unroll
            for (int kk = 0; kk < 32; ++kk) {
                bf16x8 a = *(const bf16x8*)(xt + kk * 2048);
                ax0 = MFMA16(a, *(const bf16x8*)(wxp[0] + kk * 32), ax0);
                ax1 = MFMA16(a, *(const bf16x8*)(wxp[1] + kk * 32), ax1);
            }
        }

        unsigned* hline = h1s ? (unsigned*)h1s + (size_t)t * (STEP_ELEMS / 2) + wg * 256 + wave * 64
                              : nullptr;
        gates_store<true>(ax0, ax1, cs, lane, l15, wave * 16 + lg * 4,
                          hline, out + (size_t)t * Hz + j0 + (l15 & 7), (size_t)Tz * Hz);

        if (s < Tz) publish(myflag, (unsigned)s);
    }
}

extern "C" __global__ void __launch_bounds__(256, 1)
lstm2(const float* __restrict__ x,
      const float* __restrict__ b0,
      const float* __restrict__ b1,
      __bf16* ws,
      float* out,
      __bf16* h1s,
      const __bf16* __restrict__ xhi,
      const __bf16* __restrict__ xlo)
{
    extern __shared__ char lds_raw[];
    __bf16* wtile = (__bf16*)lds_raw;
    unsigned* flags0 = (unsigned*)((char*)ws + FLAGS_BYTE);
    unsigned* flags1 = (unsigned*)((char*)ws + FLAGS_BYTE + 2048);

    if (blockIdx.x < NWG0)
        layer0(x, xhi, xlo, ws + OFF_W0XH, ws + OFF_W0XL, ws + OFF_W0H, b0,
               ws + OFF_Y0, wtile, flags0);
    else
        layer1(ws + OFF_Y0, ws + OFF_W1, b1, out, h1s, wtile, flags0, flags1);
}

extern "C" void kernel_launch(void* const* d_in, const int* in_sizes, int n_in,
                              void* d_out, int out_size, void* d_ws, size_t ws_size,
                              hipStream_t stream)
{
    const float* x  = (const float*)d_in[0];
    const float* W0 = (const float*)d_in[1];
    const float* b0 = (const float*)d_in[2];
    const float* W1 = (const float*)d_in[3];
    const float* b1 = (const float*)d_in[4];
    float* out = (float*)d_out;
    __bf16* ws = (__bf16*)d_ws;
    __bf16* h1s = (ws_size >= WS_NEED)   ? (__bf16*)((char*)ws + H1S_BYTE) : nullptr;
    __bf16* xhi = (ws_size >= WS_NEED_X) ? (__bf16*)((char*)ws + XHI_BYTE) : nullptr;
    __bf16* xlo = (ws_size >= WS_NEED_X) ? (__bf16*)((char*)ws + XLO_BYTE) : nullptr;

    (void)hipFuncSetAttribute((const void*)lstm2,
                        hipFuncAttributeMaxDynamicSharedMemorySize, (int)LDS_BYTES);

    hipLaunchKernelGGL(prep_split, dim3(2048), dim3(256), 0, stream, x, W0, W1, ws, xhi, xlo);

    const __bf16* xhic = xhi; const __bf16* xloc = xlo;
    void* args[] = { (void*)&x, (void*)&b0, (void*)&b1, (void*)&ws, (void*)&out,
                     (void*)&h1s, (void*)&xhic, (void*)&xloc };
    (void)hipLaunchCooperativeKernel(reinterpret_cast<void*>(lstm2),
                               dim3(NWGT), dim3(256), args, LDS_BYTES, stream);
}

// Round 19
// 4949.094 us; speedup vs baseline: 2.8566x; 1.8073x over previous
//
#include <hip/hip_runtime.h>
#include <hip/hip_bf16.h>

typedef __bf16 bf16x8 __attribute__((ext_vector_type(8)));
typedef float  f32x4  __attribute__((ext_vector_type(4)));

#define MFMA16(a, b, c) __builtin_amdgcn_mfma_f32_16x16x32_bf16((a), (b), (c), 0, 0, 0)

static constexpr int Bz = 64, Tz = 512, Dz = 512, Hz = 1024;
static constexpr int NWG0 = 128;
static constexpr int NWGT = 256;
static constexpr int NJ   = 8;

static constexpr int PXL = 512 + 8;
static constexpr int PHL = 1024 + 8;
static constexpr size_t LDS_BYTES = (size_t)(2 * 32 * PXL + 32 * PHL) * 2;  // 132608

// ws layout, bf16 elements
static constexpr size_t N_W0X = 4096ull * 512;
static constexpr size_t N_W0H = 4096ull * 1024;
static constexpr size_t N_W1  = 4096ull * 2048;
static constexpr size_t N_Y0  = 64ull * 512 * 1024;
static constexpr size_t N_X   = 64ull * 512 * 512;
static constexpr size_t OFF_W0XH = 0;
static constexpr size_t OFF_W0XL = OFF_W0XH + N_W0X;
static constexpr size_t OFF_W0H  = OFF_W0XL + N_W0X;
static constexpr size_t OFF_W1   = OFF_W0H  + N_W0H;
static constexpr size_t OFF_Y0   = OFF_W1   + N_W1;
static constexpr size_t FLAGS_BYTE = (((OFF_Y0 + N_Y0) * 2) + 255) & ~(size_t)255;
static constexpr size_t H1S_BYTE   = FLAGS_BYTE + 4096;
static constexpr size_t WS_NEED    = H1S_BYTE + N_Y0 * 2;
static constexpr size_t XHI_BYTE   = H1S_BYTE + N_Y0 * 2;
static constexpr size_t XLO_BYTE   = XHI_BYTE + N_X * 2;
static constexpr size_t WS_NEED_X  = XLO_BYTE + N_X * 2;

// step-major blocked h layout: elem ofs = t*65536 + wg*512 + b*8 + (col&7)
static constexpr int STEP_ELEMS = 65536;

__device__ __forceinline__ float sigm(float x) { return 1.0f / (1.0f + __expf(-x)); }

__device__ __forceinline__ void st_agent_u32(void* p, unsigned v)
{ __hip_atomic_store((unsigned*)p, v, __ATOMIC_RELAXED, __HIP_MEMORY_SCOPE_AGENT); }
__device__ __forceinline__ void st_agent_f32(float* p, float v)
{ __hip_atomic_store(p, v, __ATOMIC_RELAXED, __HIP_MEMORY_SCOPE_AGENT); }

// ---------------- prep: weights -> bf16 (hi/lo for W0x); x -> hi/lo; zero flags ------
extern "C" __global__ void prep_split(const float* __restrict__ x,
                                      const float* __restrict__ W0,
                                      const float* __restrict__ W1,
                                      __bf16* __restrict__ ws,
                                      __bf16* __restrict__ xhi,
                                      __bf16* __restrict__ xlo)
{
    if (blockIdx.x == 0)
        for (int i = threadIdx.x; i < 1024; i += 256)
            ((unsigned*)((char*)ws + FLAGS_BYTE))[i] = 0u;

    __bf16* w0xh = ws + OFF_W0XH;
    __bf16* w0xl = ws + OFF_W0XL;
    __bf16* w0h  = ws + OFF_W0H;
    __bf16* w1c  = ws + OFF_W1;
    const size_t ntot = N_W0X + N_W0H + N_W1;
    const size_t stride = (size_t)gridDim.x * blockDim.x;
    for (size_t idx = (size_t)blockIdx.x * blockDim.x + threadIdx.x;
         idx < ntot; idx += stride) {
        if (idx < N_W0X) {
            size_t r = idx >> 9, c = idx & 511;
            float w = W0[r * 1536 + c];
            __bf16 hi = (__bf16)w;
            w0xh[idx] = hi;
            w0xl[idx] = (__bf16)(w - (float)hi);
        } else if (idx < N_W0X + N_W0H) {
            size_t i = idx - N_W0X;
            size_t r = i >> 10, c = i & 1023;
            w0h[i] = (__bf16)W0[r * 1536 + 512 + c];
        } else {
            size_t i = idx - N_W0X - N_W0H;
            w1c[i] = (__bf16)W1[i];
        }
    }
    if (xhi) {
        for (size_t idx = (size_t)blockIdx.x * blockDim.x + threadIdx.x;
             idx < N_X; idx += stride) {
            float v = x[idx];
            __bf16 hi = (__bf16)v;
            xhi[idx] = hi;
            xlo[idx] = (__bf16)(v - (float)hi);
        }
    }
}

// ---------------- sync (per-wave flags) ----------------
__device__ __forceinline__ void publish(unsigned* p, unsigned v)
{
    asm volatile("s_waitcnt vmcnt(0)" ::: "memory");
    __hip_atomic_store(p, v, __ATOMIC_RELAXED, __HIP_MEMORY_SCOPE_AGENT);
}

__device__ __forceinline__ void wait_chunk32(const unsigned* flags, int base, unsigned target)
{
    const unsigned* p = flags + base + (threadIdx.x & 31);
    for (;;) {
        unsigned v = __hip_atomic_load(p, __ATOMIC_RELAXED, __HIP_MEMORY_SCOPE_AGENT);
        if (__all(v >= target)) break;
        __builtin_amdgcn_s_sleep(1);
    }
    asm volatile("" ::: "memory");
}

// x-part GEMM, pre-split inputs (no VALU split in loop)
__device__ __forceinline__ void zx_ps(const __bf16* __restrict__ xh,
                                      const __bf16* __restrict__ xl,
    const __bf16* wxh0, const __bf16* wxl0,
    const __bf16* wxh1, const __bf16* wxl1,
    f32x4& zx0, f32x4& zx1)
{
    f32x4 a0 = {0,0,0,0}, a1 = {0,0,0,0};
#pragma unroll 4
    for (int kk = 0; kk < Dz / 32; ++kk) {
        bf16x8 ahi = *(const bf16x8*)(xh + kk * 32);
        bf16x8 alo = *(const bf16x8*)(xl + kk * 32);
        bf16x8 wh0 = *(const bf16x8*)(wxh0 + kk * 32);
        bf16x8 wl0 = *(const bf16x8*)(wxl0 + kk * 32);
        bf16x8 wh1 = *(const bf16x8*)(wxh1 + kk * 32);
        bf16x8 wl1 = *(const bf16x8*)(wxl1 + kk * 32);
        a0 = MFMA16(ahi, wh0, a0); a0 = MFMA16(alo, wh0, a0); a0 = MFMA16(ahi, wl0, a0);
        a1 = MFMA16(ahi, wh1, a1); a1 = MFMA16(alo, wh1, a1); a1 = MFMA16(ahi, wl1, a1);
    }
    zx0 = a0; zx1 = a1;
}

// fallback: split on the fly (identical rounding -> identical results)
__device__ __forceinline__ void zx_fb(const float* __restrict__ xt,
    const __bf16* wxh0, const __bf16* wxl0,
    const __bf16* wxh1, const __bf16* wxl1,
    f32x4& zx0, f32x4& zx1)
{
    f32x4 a0 = {0,0,0,0}, a1 = {0,0,0,0};
#pragma unroll 4
    for (int kk = 0; kk < Dz / 32; ++kk) {
        f32x4 va = *(const f32x4*)(xt + kk * 32);
        f32x4 vb = *(const f32x4*)(xt + kk * 32 + 4);
        bf16x8 ahi, alo;
#pragma unroll
        for (int e = 0; e < 4; ++e) {
            float v = va[e]; __bf16 h1 = (__bf16)v;
            ahi[e] = h1; alo[e] = (__bf16)(v - (float)h1);
            float w = vb[e]; __bf16 h2 = (__bf16)w;
            ahi[4 + e] = h2; alo[4 + e] = (__bf16)(w - (float)h2);
        }
        bf16x8 wh0 = *(const bf16x8*)(wxh0 + kk * 32);
        bf16x8 wl0 = *(const bf16x8*)(wxl0 + kk * 32);
        bf16x8 wh1 = *(const bf16x8*)(wxh1 + kk * 32);
        bf16x8 wl1 = *(const bf16x8*)(wxl1 + kk * 32);
        a0 = MFMA16(ahi, wh0, a0); a0 = MFMA16(alo, wh0, a0); a0 = MFMA16(ahi, wl0, a0);
        a1 = MFMA16(ahi, wh1, a1); a1 = MFMA16(alo, wh1, a1); a1 = MFMA16(ahi, wl1, a1);
    }
    zx0 = a0; zx1 = a1;
}

// in-register gates + full-line blocked store (see r10/r11 derivation)
template <bool F32OUT>
__device__ __forceinline__ void gates_store(
    f32x4 za, f32x4 zb, float* cs, int lane, int l15, int rowBase,
    unsigned* yline, float* yf32, size_t rowStride)
{
    f32x4 pa, pb;
#pragma unroll
    for (int e = 0; e < 4; ++e) { pa[e] = __shfl_xor(za[e], 8, 64); pb[e] = __shfl_xor(zb[e], 8, 64); }
    const bool hi = (l15 & 8) != 0;
    int p01[2];
#pragma unroll
    for (int k2 = 0; k2 < 2; ++k2) {
        float zi, zf, zo, zg;
        if (hi) { zi = pa[2 + k2]; zf = za[2 + k2]; zo = pb[2 + k2]; zg = zb[2 + k2]; }
        else    { zi = za[k2];     zf = pa[k2];     zo = zb[k2];     zg = pb[k2];     }
        float cn = sigm(zf) * cs[k2] + sigm(zi) * tanhf(zg);
        float hn = sigm(zo) * tanhf(cn);
        cs[k2] = cn;
        if (F32OUT) {
            int b = rowBase + (hi ? 2 : 0) + k2;
            st_agent_f32(&yf32[(size_t)b * rowStride], hn);
        }
        __bf16 hb = (__bf16)hn;
        unsigned bits = (unsigned)__builtin_bit_cast(unsigned short, hb);
        unsigned par  = __shfl_down(bits, 1, 64);
        p01[k2] = (int)(bits | (par << 16));
    }
    if (yline) {
        int r    = lane >> 2;
        int srcl = ((r >> 2) << 4) | (((r >> 1) & 1) << 3) | ((lane & 3) << 1);
        unsigned v0 = (unsigned)__builtin_amdgcn_ds_bpermute(srcl * 4, p01[0]);
        unsigned v1 = (unsigned)__builtin_amdgcn_ds_bpermute(srcl * 4, p01[1]);
        st_agent_u32(yline + lane, (r & 1) ? v1 : v0);
    }
}

// ---------------- layer 0 ----------------
__device__ __forceinline__ void layer0(
    const float* __restrict__ x,
    const __bf16* __restrict__ xhi, const __bf16* __restrict__ xlo,
    const __bf16* __restrict__ w0xh, const __bf16* __restrict__ w0xl,
    const __bf16* __restrict__ w0h,  const float* __restrict__ b0,
    __bf16* y0, __bf16* wtile, unsigned* flags0)
{
    const int tid  = threadIdx.x;
    const int wave = tid >> 6, lane = tid & 63, l15 = lane & 15, lg = lane >> 4;
    const int wg   = blockIdx.x;
    const int j0   = wg * NJ;

    __bf16* sWXH = wtile;
    __bf16* sWXL = wtile + 32 * PXL;
    __bf16* sWH  = wtile + 64 * PXL;
    for (int idx = tid; idx < 32 * (Dz / 8); idx += 256) {
        int r = idx >> 6, kc = (idx & 63) * 8;
        size_t grow = (size_t)((r >> 3) * Hz + j0 + (r & 7));
        *(bf16x8*)(sWXH + r * PXL + kc) = *(const bf16x8*)(w0xh + grow * Dz + kc);
        *(bf16x8*)(sWXL + r * PXL + kc) = *(const bf16x8*)(w0xl + grow * Dz + kc);
    }
    for (int idx = tid; idx < 32 * (Hz / 8); idx += 256) {
        int r = idx >> 7, kc = (idx & 127) * 8;
        size_t grow = (size_t)((r >> 3) * Hz + j0 + (r & 7));
        *(bf16x8*)(sWH + r * PHL + kc) = *(const bf16x8*)(w0h + grow * Hz + kc);
    }
    __syncthreads();

    const __bf16* wxh[2]; const __bf16* wxl[2]; const __bf16* whp[2]; float bv[2];
#pragma unroll
    for (int tn = 0; tn < 2; ++tn) {
        int c = tn * 16 + l15;
        wxh[tn] = sWXH + c * PXL + lg * 8;
        wxl[tn] = sWXL + c * PXL + lg * 8;
        whp[tn] = sWH  + c * PHL + lg * 8;
        bv[tn]  = b0[(c >> 3) * Hz + j0 + (c & 7)];
    }
    const int bA = wave * 16 + l15;
    const float*  xp  = x + (size_t)bA * Tz * Dz + lg * 8;
    const __bf16* xph = xhi ? xhi + (size_t)bA * Tz * Dz + lg * 8 : nullptr;
    const __bf16* xpl = xlo ? xlo + (size_t)bA * Tz * Dz + lg * 8 : nullptr;
    const __bf16* hp0 = y0 + wave * 128 + l15 * 8 + lg * 512;

    const unsigned* flw = flags0 + wave * 128;
    unsigned* myflag     = flags0 + wave * 128 + wg;

    float cs[2] = {0.f, 0.f};
    f32x4 zx0, zx1;
    if (xph) zx_ps(xph, xpl, wxh[0], wxl[0], wxh[1], wxl[1], zx0, zx1);
    else     zx_fb(xp,       wxh[0], wxl[0], wxh[1], wxl[1], zx0, zx1);

    for (int s = 0; s < Tz; ++s) {
        f32x4 ah0 = {0,0,0,0}, ah1 = {0,0,0,0};
        if (s > 0) {
            const __bf16* ht = hp0 + (size_t)(s - 1) * STEP_ELEMS;
            for (int c4 = 0; c4 < 4; ++c4) {
                wait_chunk32(flw, 32 * c4, (unsigned)s);
#pragma unroll
                for (int kk = 8 * c4; kk < 8 * c4 + 8; ++kk) {
                    bf16x8 a = *(const bf16x8*)(ht + kk * 2048);
                    ah0 = MFMA16(a, *(const bf16x8*)(whp[0] + kk * 32), ah0);
                    ah1 = MFMA16(a, *(const bf16x8*)(whp[1] + kk * 32), ah1);
                }
            }
        }
        f32x4 za, zb;
#pragma unroll
        for (int e = 0; e < 4; ++e) { za[e] = zx0[e] + ah0[e] + bv[0]; zb[e] = zx1[e] + ah1[e] + bv[1]; }

        unsigned* yline = (unsigned*)y0 + (size_t)s * (STEP_ELEMS / 2) + wg * 256 + wave * 64;
        gates_store<false>(za, zb, cs, lane, l15, wave * 16 + lg * 4, yline, nullptr, 0);

        publish(myflag, (unsigned)(s + 1));
        if (s < Tz - 1) {
            if (xph) zx_ps(xph + (size_t)(s + 1) * Dz, xpl + (size_t)(s + 1) * Dz,
                           wxh[0], wxl[0], wxh[1], wxl[1], zx0, zx1);
            else     zx_fb(xp + (size_t)(s + 1) * Dz,
                           wxh[0], wxl[0], wxh[1], wxl[1], zx0, zx1);
        }
    }
}

// ---------------- layer 1 ----------------
__device__ __forceinline__ void layer1(
    const __bf16* __restrict__ y0, const __bf16* __restrict__ w1c,
    const float* __restrict__ b1, float* out, __bf16* h1s,
    __bf16* wtile, unsigned* flags0, unsigned* flags1)
{
    const int tid  = threadIdx.x;
    const int wave = tid >> 6, lane = tid & 63, l15 = lane & 15, lg = lane >> 4;
    const int wg   = blockIdx.x - NWG0;
    const int j0   = wg * NJ;

    __bf16* sWX = wtile;
    __bf16* sWH = wtile + 32 * PHL;
    for (int idx = tid; idx < 32 * (Hz / 8); idx += 256) {
        int r = idx >> 7, kc = (idx & 127) * 8;
        size_t grow = (size_t)((r >> 3) * Hz + j0 + (r & 7));
        const __bf16* srow = w1c + grow * 2048;
        *(bf16x8*)(sWX + r * PHL + kc) = *(const bf16x8*)(srow + kc);
        *(bf16x8*)(sWH + r * PHL + kc) = *(const bf16x8*)(srow + 1024 + kc);
    }
    __syncthreads();

    const __bf16* wxp[2]; const __bf16* whp[2]; float bv[2];
#pragma unroll
    for (int tn = 0; tn < 2; ++tn) {
        int c = tn * 16 + l15;
        wxp[tn] = sWX + c * PHL + lg * 8;
        whp[tn] = sWH + c * PHL + lg * 8;
        bv[tn]  = b1[(c >> 3) * Hz + j0 + (c & 7)];
    }
    const int bA = wave * 16 + l15;
    const __bf16* xp0 = y0 + wave * 128 + l15 * 8 + lg * 512;
    const float*  hpf = out + (size_t)bA * Tz * Hz + lg * 8;
    const __bf16* hs0 = h1s ? h1s + wave * 128 + l15 * 8 + lg * 512 : nullptr;

    const unsigned* fl0w = flags0 + wave * 128;
    const unsigned* fl1w = flags1 + wave * 128;
    unsigned* myflag      = flags1 + wave * 128 + wg;

    float cs[2] = {0.f, 0.f};

    for (int s = 1; s <= Tz; ++s) {
        const int t = s - 1;
        f32x4 ax0 = {bv[0], bv[0], bv[0], bv[0]};
        f32x4 ax1 = {bv[1], bv[1], bv[1], bv[1]};

        if (t > 0) {
            if (hs0) {
                const __bf16* ht = hs0 + (size_t)(t - 1) * STEP_ELEMS;
                for (int c4 = 0; c4 < 4; ++c4) {
                    wait_chunk32(fl1w, 32 * c4, (unsigned)(s - 1));
#pragma unroll
                    for (int kk = 8 * c4; kk < 8 * c4 + 8; ++kk) {
                        bf16x8 a = *(const bf16x8*)(ht + kk * 2048);
                        ax0 = MFMA16(a, *(const bf16x8*)(whp[0] + kk * 32), ax0);
                        ax1 = MFMA16(a, *(const bf16x8*)(whp[1] + kk * 32), ax1);
                    }
                }
            } else {
                const float* ht = hpf + (size_t)(t - 1) * Hz;
                for (int c4 = 0; c4 < 4; ++c4) {
                    wait_chunk32(fl1w, 32 * c4, (unsigned)(s - 1));
#pragma unroll
                    for (int kk = 8 * c4; kk < 8 * c4 + 8; ++kk) {
                        f32x4 va = *(const f32x4*)(ht + kk * 32);
                        f32x4 vb = *(const f32x4*)(ht + kk * 32 + 4);
                        bf16x8 a;
#pragma unroll
                        for (int e = 0; e < 4; ++e) { a[e] = (__bf16)va[e]; a[4 + e] = (__bf16)vb[e]; }
                        ax0 = MFMA16(a, *(const bf16x8*)(whp[0] + kk * 32), ax0);
                        ax1 = MFMA16(a, *(const bf16x8*)(whp[1] + kk * 32), ax1);
                    }
                }
            }
        }
        {
            const __bf16* xt = xp0 + (size_t)t * STEP_ELEMS;
            for (int c4 = 0; c4 < 4; ++c4) {
                wait_chunk32(fl0w, 32 * c4, (unsigned)s);
#pragma unroll
                for (int kk = 8 * c4; kk < 8 * c4 + 8; ++kk) {
                    bf16x8 a = *(const bf16x8*)(xt + kk * 2048);
                    ax0 = MFMA16(a, *(const bf16x8*)(wxp[0] + kk * 32), ax0);
                    ax1 = MFMA16(a, *(const bf16x8*)(wxp[1] + kk * 32), ax1);
                }
            }
        }

        unsigned* hline = h1s ? (unsigned*)h1s + (size_t)t * (STEP_ELEMS / 2) + wg * 256 + wave * 64
                              : nullptr;
        gates_store<true>(ax0, ax1, cs, lane, l15, wave * 16 + lg * 4,
                          hline, out + (size_t)t * Hz + j0 + (l15 & 7), (size_t)Tz * Hz);

        if (s < Tz) publish(myflag, (unsigned)s);
    }
}

extern "C" __global__ void __launch_bounds__(256, 1)
lstm2(const float* __restrict__ x,
      const float* __restrict__ b0,
      const float* __restrict__ b1,
      __bf16* ws,
      float* out,
      __bf16* h1s,
      const __bf16* __restrict__ xhi,
      const __bf16* __restrict__ xlo)
{
    extern __shared__ char lds_raw[];
    __bf16* wtile = (__bf16*)lds_raw;
    unsigned* flags0 = (unsigned*)((char*)ws + FLAGS_BYTE);
    unsigned* flags1 = (unsigned*)((char*)ws + FLAGS_BYTE + 2048);

    if (blockIdx.x < NWG0)
        layer0(x, xhi, xlo, ws + OFF_W0XH, ws + OFF_W0XL, ws + OFF_W0H, b0,
               ws + OFF_Y0, wtile, flags0);
    else
        layer1(ws + OFF_Y0, ws + OFF_W1, b1, out, h1s, wtile, flags0, flags1);
}

extern "C" void kernel_launch(void* const* d_in, const int* in_sizes, int n_in,
                              void* d_out, int out_size, void* d_ws, size_t ws_size,
                              hipStream_t stream)
{
    const float* x  = (const float*)d_in[0];
    const float* W0 = (const float*)d_in[1];
    const float* b0 = (const float*)d_in[2];
    const float* W1 = (const float*)d_in[3];
    const float* b1 = (const float*)d_in[4];
    float* out = (float*)d_out;
    __bf16* ws = (__bf16*)d_ws;
    __bf16* h1s = (ws_size >= WS_NEED)   ? (__bf16*)((char*)ws + H1S_BYTE) : nullptr;
    __bf16* xhi = (ws_size >= WS_NEED_X) ? (__bf16*)((char*)ws + XHI_BYTE) : nullptr;
    __bf16* xlo = (ws_size >= WS_NEED_X) ? (__bf16*)((char*)ws + XLO_BYTE) : nullptr;

    (void)hipFuncSetAttribute((const void*)lstm2,
                        hipFuncAttributeMaxDynamicSharedMemorySize, (int)LDS_BYTES);

    hipLaunchKernelGGL(prep_split, dim3(2048), dim3(256), 0, stream, x, W0, W1, ws, xhi, xlo);

    const __bf16* xhic = xhi; const __bf16* xloc = xlo;
    void* args[] = { (void*)&x, (void*)&b0, (void*)&b1, (void*)&ws, (void*)&out,
                     (void*)&h1s, (void*)&xhic, (void*)&xloc };
    (void)hipLaunchCooperativeKernel(reinterpret_cast<void*>(lstm2),
                               dim3(NWGT), dim3(256), args, LDS_BYTES, stream);
}